// Round 15
// baseline (84.562 us; speedup 1.0000x reference)
//
#include <hip/hip_runtime.h>
#include <hip/hip_bf16.h>

typedef __hip_bfloat16 bf16;
typedef __attribute__((ext_vector_type(8))) short bf16x8;    // 8 bf16 (MFMA A/B frag)
typedef __attribute__((ext_vector_type(4))) float f32x4;     // 16x16 C/D frag
typedef __attribute__((ext_vector_type(16))) float f32x16;   // 32x32 C/D frag
typedef __attribute__((ext_vector_type(2))) unsigned uintx2; // permlane32_swap ret

#define DEV static __device__ __forceinline__

DEV void gload_lds16(const void* g, void* l) {
  __builtin_amdgcn_global_load_lds((const __attribute__((address_space(1))) void*)g,
                                   (__attribute__((address_space(3))) void*)l, 16, 0, 0);
}

DEV f32x4 mfma16(bf16x8 a, bf16x8 b, f32x4 c) {
  return __builtin_amdgcn_mfma_f32_16x16x32_bf16(a, b, c, 0, 0, 0);
}
DEV f32x16 mfma32(bf16x8 a, bf16x8 b, f32x16 c) {
  return __builtin_amdgcn_mfma_f32_32x32x16_bf16(a, b, c, 0, 0, 0);
}

DEV float ex2(float x) { return __builtin_amdgcn_exp2f(x); }  // bare v_exp_f32

DEV unsigned cvt_pk(float lo, float hi) {   // packed f32x2 -> bf16x2 (RNE)
  unsigned r;
  asm("v_cvt_pk_bf16_f32 %0, %1, %2" : "=v"(r) : "v"(lo), "v"(hi));
  return r;
}

DEV unsigned short f2b_bits(float f) {  // RNE f32->bf16 (inputs are finite)
  unsigned int u = __float_as_uint(f);
  return (unsigned short)((u + 0x7fffu + ((u >> 16) & 1u)) >> 16);
}

DEV float b2f(unsigned short b) { return __uint_as_float((unsigned)b << 16); }

// ------- prep: merged f32->bf16 (X, Wqkv, Wo) + RoPE cos/sin table -------

__global__ void prep_kernel(const float4* __restrict__ x, const float4* __restrict__ wq,
                            const float4* __restrict__ wo, ushort4* __restrict__ xb,
                            ushort4* __restrict__ wqb, ushort4* __restrict__ wob,
                            float2* __restrict__ tab) {
  int i = blockIdx.x * 256 + threadIdx.x;
  if (i >= 1310720) {                     // rope table part (256 trailing blocks)
    int idx = i - 1310720;                // s*32 + j
    int s = idx >> 5, j = idx & 31;
    float inv = exp2f(-(float)(2 * j) * (13.287712379549449f / 64.0f));
    float a = (float)s * inv;
    tab[idx] = make_float2(cosf(a), sinf(a));
    return;
  }
  const float4* s; ushort4* d; int off;
  if (i < 1048576)      { s = x;  d = xb;  off = i; }            // 8192*512/4
  else if (i < 1245184) { s = wq; d = wqb; off = i - 1048576; }  // +1536*512/4
  else                  { s = wo; d = wob; off = i - 1245184; }  // +512*512/4
  float4 v = s[off];
  ushort4 o;
  o.x = f2b_bits(v.x); o.y = f2b_bits(v.y); o.z = f2b_bits(v.z); o.w = f2b_bits(v.w);
  d[off] = o;
}

// ---------------- QKV GEMM with fused RoPE / V-transpose epilogue ----------------

__global__ __launch_bounds__(256)
void gemm_qkv_kernel(const bf16* __restrict__ A, const bf16* __restrict__ Bt,
                     const float* __restrict__ bias, const float2* __restrict__ tab,
                     bf16* __restrict__ Qo, bf16* __restrict__ Ko, bf16* __restrict__ VTo)
{
  __shared__ bf16 SH[128 * 136];        // 34 KB; K-loop staging aliases front 32 KB
  const int K = 512;
  const int t = threadIdx.x;
  const int lane = t & 63;
  const int wave = t >> 6;
  const int wm = (wave >> 1) * 64;
  const int wn = (wave & 1) * 64;
  const int bm = blockIdx.x * 128;
  const int bn = blockIdx.y * 128;
  const int qkv = bn >> 9;              // 0=Q 1=K 2=V (block-uniform)
  const int local0 = bn & 511;

  const int r4 = t >> 2;
  const int c8 = (t & 3) * 8;
  const bf16* Ag = A + (size_t)(bm + r4) * K + c8;
  const bf16* Bg = Bt + (size_t)(bn + r4) * K + c8;

  f32x4 acc[4][4] = {};
  const int rr = lane & 15;
  const int kg = (lane >> 4) * 8;

  // staging layout (elements): A buf0 @0, A buf1 @4096, B buf0 @8192, B buf1 @12288
  auto stage = [&](int buf, int k0) {
    bf16* Asl = SH + buf * 4096 + t * 8;
    bf16* Bsl = SH + 8192 + buf * 4096 + t * 8;
    gload_lds16(Ag + k0, Asl);
    gload_lds16(Ag + (size_t)64 * K + k0, Asl + 2048);
    gload_lds16(Bg + k0, Bsl);
    gload_lds16(Bg + (size_t)64 * K + k0, Bsl + 2048);
  };

  stage(0, 0);
  int cur = 0;
  for (int k0 = 0; k0 < K; k0 += 32) {
    __syncthreads();                    // implicit vmcnt(0): buf[cur] ready
    if (k0 + 32 < K) stage(cur ^ 1, k0 + 32);   // overlap next loads w/ compute
    const bf16* Asb = SH + cur * 4096;
    const bf16* Bsb = SH + 8192 + cur * 4096;
    bf16x8 af[4], bfr[4];
#pragma unroll
    for (int m = 0; m < 4; ++m) af[m] = *(const bf16x8*)&Asb[(wm + m * 16 + rr) * 32 + kg];
#pragma unroll
    for (int n = 0; n < 4; ++n) bfr[n] = *(const bf16x8*)&Bsb[(wn + n * 16 + rr) * 32 + kg];
#pragma unroll
    for (int m = 0; m < 4; ++m)
#pragma unroll
      for (int n = 0; n < 4; ++n)
        acc[m][n] = mfma16(af[m], bfr[n], acc[m][n]);
    cur ^= 1;
  }
  __syncthreads();                      // all reads of staging done; SH reusable

  const int rg = (lane >> 4) * 4;
  float bv4[4];
#pragma unroll
  for (int n = 0; n < 4; ++n) bv4[n] = bias[bn + wn + n * 16 + rr];

  // phase 1: biased tile -> LDS [s][136]
#pragma unroll
  for (int n = 0; n < 4; ++n)
#pragma unroll
    for (int m = 0; m < 4; ++m)
#pragma unroll
      for (int r = 0; r < 4; ++r)
        SH[(wm + m * 16 + rg + r) * 136 + (wn + n * 16 + rr)] =
            __float2bfloat16(acc[m][n][r] + bv4[n]);
  __syncthreads();

  const int bv_ = bm >> 11;             // which (b,v)
  const int s0 = bm & 2047;
  const int d0 = local0 >> 3;           // 0,16,32,48

  if (qkv == 2) {
    // V: transpose out of LDS. thread = (local feature p, s-half).
    const int p = t & 127;              // p = dl*8 + hh
    const int sh = (t >> 7) * 64;
    const int dl = p >> 3, hh = p & 7;
    bf16* dst = VTo + (size_t)(bv_ * 8 + hh) * (2048 * 64)
                    + (size_t)(d0 + dl) * 2048 + s0 + sh;
#pragma unroll
    for (int g = 0; g < 8; ++g) {
      union { unsigned short u[8]; ushort4 q[2]; } o;
#pragma unroll
      for (int k = 0; k < 8; ++k)
        o.u[k] = *(const unsigned short*)&SH[(sh + g * 8 + k) * 136 + p];
      *(ushort4*)(dst + g * 8)     = o.q[0];
      *(ushort4*)(dst + g * 8 + 4) = o.q[1];
    }
    return;
  }

  // phase 2 (Q/K): rope, vectorized. unit = (s-row sl, d-quad jq)
  bf16* dst0 = (qkv == 0) ? Qo : Ko;
  const float scale = (qkv == 0) ? 0.18033688011112042f : 1.0f;  // Q: 1/8*log2(e)
#pragma unroll
  for (int pass = 0; pass < 2; ++pass) {
    const int u = pass * 256 + t;
    const int sl = u >> 2;              // 0..127
    const int jq = u & 3;               // d-quad: d = d0+4jq .. +3
    const int sg = s0 + sl;
    const bf16* rowp = &SH[sl * 136 + jq * 32];
    bf16x8 x0 = *(const bf16x8*)(rowp);        // d = d0+4jq (h=0..7)
    bf16x8 x1 = *(const bf16x8*)(rowp + 8);    // d+1
    bf16x8 x2 = *(const bf16x8*)(rowp + 16);   // d+2
    bf16x8 x3 = *(const bf16x8*)(rowp + 24);   // d+3
    const float4 cs = *(const float4*)&tab[((size_t)sg << 5) + (d0 >> 1) + jq * 2];
#pragma unroll
    for (int h = 0; h < 8; ++h) {
      const float ve0 = b2f((unsigned short)x0[h]);
      const float vo0 = b2f((unsigned short)x1[h]);
      const float ve1 = b2f((unsigned short)x2[h]);
      const float vo1 = b2f((unsigned short)x3[h]);
      ushort4 o;
      o.x = f2b_bits((ve0 * cs.x - vo0 * cs.y) * scale);
      o.y = f2b_bits((vo0 * cs.x + ve0 * cs.y) * scale);
      o.z = f2b_bits((ve1 * cs.z - vo1 * cs.w) * scale);
      o.w = f2b_bits((vo1 * cs.z + ve1 * cs.w) * scale);
      *(ushort4*)(dst0 + (size_t)(bv_ * 8 + h) * (2048 * 64)
                       + (size_t)sg * 64 + d0 + jq * 4) = o;
    }
  }
}

// ------- output projection GEMM: 64x128 tiles, dbuf staging, f32 out -------

__global__ __launch_bounds__(256)
void gemm_o_kernel(const bf16* __restrict__ A, const bf16* __restrict__ Bt,
                   const float* __restrict__ bias, float* __restrict__ C)
{
  __shared__ bf16 As[2][64 * 32];
  __shared__ bf16 Bs[2][128 * 32];
  const int K = 512, N = 512;
  const int t = threadIdx.x;
  const int lane = t & 63;
  const int wave = t >> 6;
  const int wm = (wave >> 1) * 32;
  const int wn = (wave & 1) * 64;
  const int bm = blockIdx.x * 64;
  const int bn = blockIdx.y * 128;

  const int r4 = t >> 2;               // 0..63
  const int c8 = (t & 3) * 8;
  const bf16* Ag = A + (size_t)(bm + r4) * K + c8;
  const bf16* Bg = Bt + (size_t)(bn + r4) * K + c8;

  f32x4 acc[2][4] = {};
  const int rr = lane & 15;
  const int kg = (lane >> 4) * 8;

  auto stage = [&](int buf, int k0) {
    gload_lds16(Ag + k0, &As[buf][t * 8]);
    gload_lds16(Bg + k0, &Bs[buf][t * 8]);
    gload_lds16(Bg + (size_t)64 * K + k0, &Bs[buf][2048 + t * 8]);
  };

  stage(0, 0);
  int cur = 0;
  for (int k0 = 0; k0 < K; k0 += 32) {
    __syncthreads();
    if (k0 + 32 < K) stage(cur ^ 1, k0 + 32);
    bf16x8 af[2], bfr[4];
#pragma unroll
    for (int m = 0; m < 2; ++m) af[m] = *(const bf16x8*)&As[cur][(wm + m * 16 + rr) * 32 + kg];
#pragma unroll
    for (int n = 0; n < 4; ++n) bfr[n] = *(const bf16x8*)&Bs[cur][(wn + n * 16 + rr) * 32 + kg];
#pragma unroll
    for (int m = 0; m < 2; ++m)
#pragma unroll
      for (int n = 0; n < 4; ++n)
        acc[m][n] = mfma16(af[m], bfr[n], acc[m][n]);
    cur ^= 1;
  }

  const int rg = (lane >> 4) * 4;
#pragma unroll
  for (int n = 0; n < 4; ++n) {
    const int col = bn + wn + n * 16 + rr;
    const float bv = bias[col];
#pragma unroll
    for (int m = 0; m < 2; ++m)
#pragma unroll
      for (int r = 0; r < 4; ++r)
        C[(size_t)(bm + wm + m * 16 + rg + r) * N + col] = acc[m][n][r] + bv;
  }
}

// ---------------- causal flash attention (32x32 swapped, K-split) ----------------
// exp2-domain softmax with native v_exp_f32; P->A-frag via cvt_pk +
// permlane32_swap (T12). NEW: row-sum denominator computed IN THE MATRIX PIPE:
// lsa = mfma32(pa, ones, lsa) per k-slice -> lsa[r] = full row sum for row
// crow(r,hi) (all 32 cols identical). Removes the 32 chained v_adds/iter and
// the epilogue cross-lane reduce; denominator now sums the same bf16-rounded
// P as the PV numerator.

struct Item { unsigned char t, c, n, s; };  // tile, chunk, nblk, split?
__device__ __constant__ Item g_items[30] = {
  {5,0,12,0},{6,0,12,1},{7,0,12,1},{8,0,12,1},{9,0,12,1},{10,0,12,1},
  {11,0,12,1},{11,1,12,1},{12,0,12,1},{12,1,12,1},{13,0,12,1},{13,1,12,1},
  {14,0,12,1},{14,1,12,1},{15,0,12,1},{15,1,12,1},
  {4,0,10,0},{10,1,10,1},
  {3,0,8,0},{9,1,8,1},{15,2,8,1},
  {2,0,6,0},{8,1,6,1},{14,2,6,1},
  {1,0,4,0},{7,1,4,1},{13,2,4,1},
  {0,0,2,0},{6,1,2,1},{12,2,2,1}
};

__global__ __launch_bounds__(256, 4)
void attn_kernel(const bf16* __restrict__ Q, const bf16* __restrict__ K,
                 const bf16* __restrict__ VT, bf16* __restrict__ O,
                 bf16* __restrict__ PO, float* __restrict__ PML)
{
  __shared__ bf16 Kt[2][64 * 64];   // [k-row][d], chunk-XOR swizzled
  __shared__ bf16 Vt[2][64 * 64];   // [d][k],   chunk-XOR swizzled

  const int t = threadIdx.x;
  const int lane = t & 63;
  const int w = t >> 6;
  const int bvh = blockIdx.x;              // linear%8 = bvh%8 -> L2 locality
  const Item it = g_items[blockIdx.y];     // LPT: big items dispatched first
  const int tile = it.t, chunk = it.c, nblk = it.n, split = it.s;
  const int bv = bvh >> 3, h = bvh & 7;
  const size_t base = (size_t)bvh * (2048 * 64);

  const int q = lane & 31;                 // owned S^T column / V d-offset
  const int hi = lane >> 5;
  const int q0w = tile * 128 + w * 32;     // wave's first q-row
  const int qg = q0w + q;                  // lane's q-row
  const int kb0 = chunk * 12;              // first K-block of this chunk

  // ones as bf16x8 (B operand for the row-sum MFMA)
  union { unsigned u[4]; bf16x8 v; } ones_;
  ones_.u[0] = ones_.u[1] = ones_.u[2] = ones_.u[3] = 0x3F803F80u;
  const bf16x8 ones = ones_.v;

  // Q fragments: B-operand of mfma32
  bf16x8 qf[4];
#pragma unroll
  for (int ds = 0; ds < 4; ++ds)
    qf[ds] = *(const bf16x8*)&Q[base + (size_t)(q0w + q) * 64 + ds * 16 + hi * 8];

  f32x16 o0 = {}, o1 = {};                 // O[q'][d], d-tiles 0/1
  f32x16 lsa = {};                         // row-sum accumulator (denominator)
  float Mx = -INFINITY;

  const int sr = t >> 3;                   // staging row 0..31 (x2)
  const int sc = t & 7;                    // staging 16B chunk

  auto stage = [&](int buf, int kb) {
#pragma unroll
    for (int i = 0; i < 2; ++i) {
      int r = i * 32 + sr;
      int g = (sc ^ (r & 7)) * 8;          // pre-swizzled source col
      gload_lds16(&K[base + (size_t)(kb * 64 + r) * 64 + g], &Kt[buf][(i * 256 + t) * 8]);
      gload_lds16(&VT[base + (size_t)r * 2048 + kb * 64 + g], &Vt[buf][(i * 256 + t) * 8]);
    }
  };

  stage(0, kb0);
  int cur = 0;

#pragma unroll 1
  for (int i = 0; i < nblk; ++i) {
    const int kb = kb0 + i;
    __syncthreads();                       // implicit vmcnt(0): buf[cur] ready
    if (i + 1 < nblk) stage(cur ^ 1, kb + 1);

    if (kb * 64 <= q0w + 31) {             // wave has unmasked work
      // S^T = K Q  (64 k-rows x 32 q-cols)
      f32x16 s0 = {}, s1 = {};
      __builtin_amdgcn_s_setprio(1);
#pragma unroll
      for (int ds = 0; ds < 4; ++ds) {
        const int ck = ds * 2 + hi;
        bf16x8 k0 = *(const bf16x8*)&Kt[cur][q * 64 + ((ck ^ (q & 7)) * 8)];
        bf16x8 k1 = *(const bf16x8*)&Kt[cur][(32 + q) * 64 + ((ck ^ (q & 7)) * 8)];
        s0 = mfma32(k0, qf[ds], s0);
        s1 = mfma32(k1, qf[ds], s1);
      }
      __builtin_amdgcn_s_setprio(0);

      // mask whenever this K-block's max k exceeds the wave's MIN q-row
      if (kb * 64 + 63 > q0w) {
#pragma unroll
        for (int r = 0; r < 16; ++r) {
          const int k0i = kb * 64 + (r & 3) + 8 * (r >> 2) + 4 * hi;
          s0[r] = (k0i      <= qg) ? s0[r] : -INFINITY;
          s1[r] = (k0i + 32 <= qg) ? s1[r] : -INFINITY;
        }
      }

      // defer-max (THR = 8*log2e in exp2 domain)
      float pmax = -INFINITY;
#pragma unroll
      for (int r = 0; r < 16; ++r) pmax = fmaxf(pmax, fmaxf(s0[r], s1[r]));
      const float pm2 = fmaxf(pmax, __shfl_xor(pmax, 32));
      if (__any(pm2 > Mx + 11.541560327111707f)) {   // rare: full rescale
        const float newM = fmaxf(Mx, pm2);
        const float alpha = ex2(Mx - newM);
        Mx = newM;
#pragma unroll
        for (int r = 0; r < 16; ++r) {
          const float ar = __shfl(alpha, (r & 3) + 8 * (r >> 2) + 4 * hi);
          o0[r] *= ar;
          o1[r] *= ar;
          lsa[r] *= ar;
        }
      }

      // P = exp2(S^T - Mx): bare v_exp_f32 (Mx lane-local; no serial sum)
#pragma unroll
      for (int r = 0; r < 16; ++r) {
        s0[r] = ex2(s0[r] - Mx);
        s1[r] = ex2(s1[r] - Mx);
      }

      // O += P V ; lsa += P 1  (row-sums in the matrix pipe)
      __builtin_amdgcn_s_setprio(1);
#pragma unroll
      for (int T = 0; T < 2; ++T) {
#pragma unroll
        for (int e = 0; e < 2; ++e) {
          float v0, v1, v2, v3, v4, v5, v6, v7;
          if (T == 0) {
            v0 = s0[e*8+0]; v1 = s0[e*8+1]; v2 = s0[e*8+2]; v3 = s0[e*8+3];
            v4 = s0[e*8+4]; v5 = s0[e*8+5]; v6 = s0[e*8+6]; v7 = s0[e*8+7];
          } else {
            v0 = s1[e*8+0]; v1 = s1[e*8+1]; v2 = s1[e*8+2]; v3 = s1[e*8+3];
            v4 = s1[e*8+4]; v5 = s1[e*8+5]; v6 = s1[e*8+6]; v7 = s1[e*8+7];
          }
          const unsigned a = cvt_pk(v0, v1);
          const unsigned b = cvt_pk(v2, v3);
          const unsigned c = cvt_pk(v4, v5);
          const unsigned d = cvt_pk(v6, v7);
          const uintx2 s02 = __builtin_amdgcn_permlane32_swap(a, c, false, false);
          const uintx2 s13 = __builtin_amdgcn_permlane32_swap(b, d, false, false);
          union { unsigned u[4]; bf16x8 v; } pa;
          pa.u[0] = s02[0];  pa.u[1] = s13[0];
          pa.u[2] = s02[1];  pa.u[3] = s13[1];
          const int ck = (T * 2 + e) * 2 + hi;
          bf16x8 vf0 = *(const bf16x8*)&Vt[cur][q * 64 + ((ck ^ (q & 7)) * 8)];
          bf16x8 vf1 = *(const bf16x8*)&Vt[cur][(32 + q) * 64 + ((ck ^ (q & 7)) * 8)];
          o0 = mfma32(pa.v, vf0, o0);
          o1 = mfma32(pa.v, vf1, o1);
          lsa = mfma32(pa.v, ones, lsa);
        }
      }
      __builtin_amdgcn_s_setprio(0);
    }
    cur ^= 1;
  }

  if (split) {
    // partial epilogue: raw bf16 O + per-row (m, l) -> workspace (m in exp2 dom)
    const int slot = (tile - 6) * 3 + chunk;          // 0..29
    bf16* po = PO + ((size_t)bvh * 30 + slot) * (128 * 64);
    float* pml = PML + ((size_t)bvh * 30 + slot) * 256;
    if (hi == 0) pml[w * 32 + q] = Mx;     // Mx identical across the hi-pair
    if (q == 0) {                          // col-0 lanes hold all 32 row sums
#pragma unroll
      for (int r = 0; r < 16; ++r)
        pml[128 + w * 32 + ((r & 3) + 8 * (r >> 2) + 4 * hi)] = lsa[r];
    }
#pragma unroll
    for (int r = 0; r < 16; ++r) {
      const int qp = (r & 3) + 8 * (r >> 2) + 4 * hi;
      po[(size_t)(w * 32 + qp) * 64 + q]      = __float2bfloat16(o0[r]);
      po[(size_t)(w * 32 + qp) * 64 + 32 + q] = __float2bfloat16(o1[r]);
    }
  } else {
    // direct epilogue: per-row denominators already in lsa[r]
#pragma unroll
    for (int r = 0; r < 16; ++r) {
      const int qp = (r & 3) + 8 * (r >> 2) + 4 * hi;
      const float ir = __builtin_amdgcn_rcpf(lsa[r]);
      const size_t ob = ((size_t)bv * 2048 + q0w + qp) * 512 + h * 64;
      O[ob + q]      = __float2bfloat16(o0[r] * ir);
      O[ob + 32 + q] = __float2bfloat16(o1[r] * ir);
    }
  }
}

// ---------------- combine partials for split tiles (t = 6..15) ----------------

__global__ __launch_bounds__(256)
void combine_kernel(const bf16* __restrict__ PO, const float* __restrict__ PML,
                    bf16* __restrict__ O)
{
  const int t = 6 + blockIdx.x;            // tile 6..15
  const int bvh = blockIdx.y;
  const int nch = (t <= 11) ? 2 : 3;       // chunks per tile
  const int bv = bvh >> 3, h = bvh & 7;
  const int row = threadIdx.x >> 1;        // 0..127
  const int c0 = (threadIdx.x & 1) * 32;   // col half
  const size_t pbase = (size_t)bvh * 30 + (size_t)(t - 6) * 3;

  float mc[3], lc[3];
#pragma unroll
  for (int c = 0; c < 3; ++c) { mc[c] = -INFINITY; lc[c] = 0.0f; }
#pragma unroll
  for (int c = 0; c < 3; ++c) if (c < nch) {
    mc[c] = PML[(pbase + c) * 256 + row];
    lc[c] = PML[(pbase + c) * 256 + 128 + row];
  }
  const float m = fmaxf(fmaxf(mc[0], mc[1]), mc[2]);
  float wgt[3], l = 0.0f;
#pragma unroll
  for (int c = 0; c < 3; ++c) {
    wgt[c] = (c < nch) ? __builtin_amdgcn_exp2f(mc[c] - m) : 0.0f;  // exp2 dom
    l += wgt[c] * lc[c];
  }
  const float inv = 1.0f / l;

  float acc[32];
#pragma unroll
  for (int j = 0; j < 32; ++j) acc[j] = 0.0f;
#pragma unroll
  for (int c = 0; c < 3; ++c) if (c < nch) {
    const bf16* p = PO + (pbase + c) * (128 * 64) + (size_t)row * 64 + c0;
#pragma unroll
    for (int v = 0; v < 4; ++v) {
      bf16x8 x = *(const bf16x8*)&p[v * 8];
#pragma unroll
      for (int j = 0; j < 8; ++j) {
        const float f = __uint_as_float((unsigned)(unsigned short)x[j] << 16);
        acc[v * 8 + j] += wgt[c] * f;
      }
    }
  }
  const size_t ob = ((size_t)bv * 2048 + (size_t)t * 128 + row) * 512 + h * 64 + c0;
#pragma unroll
  for (int j = 0; j < 32; ++j) O[ob + j] = __float2bfloat16(acc[j] * inv);
}

// ---------------- launch ----------------

extern "C" void kernel_launch(void* const* d_in, const int* in_sizes, int n_in,
                              void* d_out, int out_size, void* d_ws, size_t ws_size,
                              hipStream_t stream)
{
  const float* x    = (const float*)d_in[1];
  const float* wqkv = (const float*)d_in[2];
  const float* bqkv = (const float*)d_in[3];
  const float* wo   = (const float*)d_in[4];
  const float* bo   = (const float*)d_in[5];
  float* out = (float*)d_out;

  char* p = (char*)d_ws;
  bf16* Xb   = (bf16*)p; p += (size_t)8192 * 512 * 2;      // dead after gemm_qkv
  bf16* Wqb  = (bf16*)p; p += (size_t)1536 * 512 * 2;
  bf16* Wob  = (bf16*)p; p += (size_t)512 * 512 * 2;
  bf16* SCR  = (bf16*)p; p += (size_t)8192 * 1536 * 2;     // PO scratch
  bf16* Qr   = (bf16*)p; p += (size_t)32 * 2048 * 64 * 2;
  bf16* Kr   = (bf16*)p; p += (size_t)32 * 2048 * 64 * 2;
  bf16* VTr  = (bf16*)p; p += (size_t)32 * 2048 * 64 * 2;
  bf16* Ob   = (bf16*)p; p += (size_t)8192 * 512 * 2;
  float2* tab = (float2*)p; p += (size_t)2048 * 32 * 8;

  // attention partials (stream-ordered reuse of dead regions):
  float* PML = (float*)Xb;                 // <1 MB  (Xb dead after gemm_qkv)
  bf16*  PO  = SCR;                        // ~16 MB

  prep_kernel<<<5376, 256, 0, stream>>>((const float4*)x, (const float4*)wqkv,
                                        (const float4*)wo, (ushort4*)Xb,
                                        (ushort4*)Wqb, (ushort4*)Wob, tab);

  gemm_qkv_kernel<<<dim3(64, 12), 256, 0, stream>>>(Xb, Wqb, bqkv, tab, Qr, Kr, VTr);
  attn_kernel<<<dim3(32, 30), 256, 0, stream>>>(Qr, Kr, VTr, Ob, PO, PML);
  combine_kernel<<<dim3(10, 32), 256, 0, stream>>>(PO, PML, Ob);
  gemm_o_kernel<<<dim3(128, 4), 256, 0, stream>>>(Ob, Wob, bo, out);
}

// Round 16
// 82.605 us; speedup vs baseline: 1.0237x; 1.0237x over previous
//
#include <hip/hip_runtime.h>
#include <hip/hip_bf16.h>

typedef __hip_bfloat16 bf16;
typedef __attribute__((ext_vector_type(8))) short bf16x8;    // 8 bf16 (MFMA A/B frag)
typedef __attribute__((ext_vector_type(4))) float f32x4;     // 16x16 C/D frag
typedef __attribute__((ext_vector_type(16))) float f32x16;   // 32x32 C/D frag
typedef __attribute__((ext_vector_type(2))) unsigned uintx2; // permlane32_swap ret

#define DEV static __device__ __forceinline__

DEV void gload_lds16(const void* g, void* l) {
  __builtin_amdgcn_global_load_lds((const __attribute__((address_space(1))) void*)g,
                                   (__attribute__((address_space(3))) void*)l, 16, 0, 0);
}

DEV f32x4 mfma16(bf16x8 a, bf16x8 b, f32x4 c) {
  return __builtin_amdgcn_mfma_f32_16x16x32_bf16(a, b, c, 0, 0, 0);
}
DEV f32x16 mfma32(bf16x8 a, bf16x8 b, f32x16 c) {
  return __builtin_amdgcn_mfma_f32_32x32x16_bf16(a, b, c, 0, 0, 0);
}

DEV float ex2(float x) { return __builtin_amdgcn_exp2f(x); }  // bare v_exp_f32

DEV unsigned cvt_pk(float lo, float hi) {   // packed f32x2 -> bf16x2 (RNE)
  unsigned r;
  asm("v_cvt_pk_bf16_f32 %0, %1, %2" : "=v"(r) : "v"(lo), "v"(hi));
  return r;
}

DEV unsigned short f2b_bits(float f) {  // RNE f32->bf16 (inputs are finite)
  unsigned int u = __float_as_uint(f);
  return (unsigned short)((u + 0x7fffu + ((u >> 16) & 1u)) >> 16);
}

DEV float b2f(unsigned short b) { return __uint_as_float((unsigned)b << 16); }

// ------- prep: merged f32->bf16 (X, Wqkv, Wo) + RoPE cos/sin table -------

__global__ void prep_kernel(const float4* __restrict__ x, const float4* __restrict__ wq,
                            const float4* __restrict__ wo, ushort4* __restrict__ xb,
                            ushort4* __restrict__ wqb, ushort4* __restrict__ wob,
                            float2* __restrict__ tab) {
  int i = blockIdx.x * 256 + threadIdx.x;
  if (i >= 1310720) {                     // rope table part (256 trailing blocks)
    int idx = i - 1310720;                // s*32 + j
    int s = idx >> 5, j = idx & 31;
    float inv = exp2f(-(float)(2 * j) * (13.287712379549449f / 64.0f));
    float a = (float)s * inv;
    tab[idx] = make_float2(cosf(a), sinf(a));
    return;
  }
  const float4* s; ushort4* d; int off;
  if (i < 1048576)      { s = x;  d = xb;  off = i; }            // 8192*512/4
  else if (i < 1245184) { s = wq; d = wqb; off = i - 1048576; }  // +1536*512/4
  else                  { s = wo; d = wob; off = i - 1245184; }  // +512*512/4
  float4 v = s[off];
  ushort4 o;
  o.x = f2b_bits(v.x); o.y = f2b_bits(v.y); o.z = f2b_bits(v.z); o.w = f2b_bits(v.w);
  d[off] = o;
}

// ---------------- QKV GEMM with fused RoPE / V-transpose epilogue ----------------

__global__ __launch_bounds__(256)
void gemm_qkv_kernel(const bf16* __restrict__ A, const bf16* __restrict__ Bt,
                     const float* __restrict__ bias, const float2* __restrict__ tab,
                     bf16* __restrict__ Qo, bf16* __restrict__ Ko, bf16* __restrict__ VTo)
{
  __shared__ bf16 SH[128 * 136];        // 34 KB; K-loop staging aliases front 32 KB
  const int K = 512;
  const int t = threadIdx.x;
  const int lane = t & 63;
  const int wave = t >> 6;
  const int wm = (wave >> 1) * 64;
  const int wn = (wave & 1) * 64;
  const int bm = blockIdx.x * 128;
  const int bn = blockIdx.y * 128;
  const int qkv = bn >> 9;              // 0=Q 1=K 2=V (block-uniform)
  const int local0 = bn & 511;

  const int r4 = t >> 2;
  const int c8 = (t & 3) * 8;
  const bf16* Ag = A + (size_t)(bm + r4) * K + c8;
  const bf16* Bg = Bt + (size_t)(bn + r4) * K + c8;

  f32x4 acc[4][4] = {};
  const int rr = lane & 15;
  const int kg = (lane >> 4) * 8;

  // staging layout (elements): A buf0 @0, A buf1 @4096, B buf0 @8192, B buf1 @12288
  auto stage = [&](int buf, int k0) {
    bf16* Asl = SH + buf * 4096 + t * 8;
    bf16* Bsl = SH + 8192 + buf * 4096 + t * 8;
    gload_lds16(Ag + k0, Asl);
    gload_lds16(Ag + (size_t)64 * K + k0, Asl + 2048);
    gload_lds16(Bg + k0, Bsl);
    gload_lds16(Bg + (size_t)64 * K + k0, Bsl + 2048);
  };

  stage(0, 0);
  int cur = 0;
  for (int k0 = 0; k0 < K; k0 += 32) {
    __syncthreads();                    // implicit vmcnt(0): buf[cur] ready
    if (k0 + 32 < K) stage(cur ^ 1, k0 + 32);   // overlap next loads w/ compute
    const bf16* Asb = SH + cur * 4096;
    const bf16* Bsb = SH + 8192 + cur * 4096;
    bf16x8 af[4], bfr[4];
#pragma unroll
    for (int m = 0; m < 4; ++m) af[m] = *(const bf16x8*)&Asb[(wm + m * 16 + rr) * 32 + kg];
#pragma unroll
    for (int n = 0; n < 4; ++n) bfr[n] = *(const bf16x8*)&Bsb[(wn + n * 16 + rr) * 32 + kg];
#pragma unroll
    for (int m = 0; m < 4; ++m)
#pragma unroll
      for (int n = 0; n < 4; ++n)
        acc[m][n] = mfma16(af[m], bfr[n], acc[m][n]);
    cur ^= 1;
  }
  __syncthreads();                      // all reads of staging done; SH reusable

  const int rg = (lane >> 4) * 4;
  float bv4[4];
#pragma unroll
  for (int n = 0; n < 4; ++n) bv4[n] = bias[bn + wn + n * 16 + rr];

  // phase 1: biased tile -> LDS [s][136]
#pragma unroll
  for (int n = 0; n < 4; ++n)
#pragma unroll
    for (int m = 0; m < 4; ++m)
#pragma unroll
      for (int r = 0; r < 4; ++r)
        SH[(wm + m * 16 + rg + r) * 136 + (wn + n * 16 + rr)] =
            __float2bfloat16(acc[m][n][r] + bv4[n]);
  __syncthreads();

  const int bv_ = bm >> 11;             // which (b,v)
  const int s0 = bm & 2047;
  const int d0 = local0 >> 3;           // 0,16,32,48

  if (qkv == 2) {
    // V: transpose out of LDS. thread = (local feature p, s-half).
    const int p = t & 127;              // p = dl*8 + hh
    const int sh = (t >> 7) * 64;
    const int dl = p >> 3, hh = p & 7;
    bf16* dst = VTo + (size_t)(bv_ * 8 + hh) * (2048 * 64)
                    + (size_t)(d0 + dl) * 2048 + s0 + sh;
#pragma unroll
    for (int g = 0; g < 8; ++g) {
      union { unsigned short u[8]; ushort4 q[2]; } o;
#pragma unroll
      for (int k = 0; k < 8; ++k)
        o.u[k] = *(const unsigned short*)&SH[(sh + g * 8 + k) * 136 + p];
      *(ushort4*)(dst + g * 8)     = o.q[0];
      *(ushort4*)(dst + g * 8 + 4) = o.q[1];
    }
    return;
  }

  // phase 2 (Q/K): rope, vectorized. unit = (s-row sl, d-quad jq)
  bf16* dst0 = (qkv == 0) ? Qo : Ko;
  const float scale = (qkv == 0) ? 0.18033688011112042f : 1.0f;  // Q: 1/8*log2(e)
#pragma unroll
  for (int pass = 0; pass < 2; ++pass) {
    const int u = pass * 256 + t;
    const int sl = u >> 2;              // 0..127
    const int jq = u & 3;               // d-quad: d = d0+4jq .. +3
    const int sg = s0 + sl;
    const bf16* rowp = &SH[sl * 136 + jq * 32];
    bf16x8 x0 = *(const bf16x8*)(rowp);        // d = d0+4jq (h=0..7)
    bf16x8 x1 = *(const bf16x8*)(rowp + 8);    // d+1
    bf16x8 x2 = *(const bf16x8*)(rowp + 16);   // d+2
    bf16x8 x3 = *(const bf16x8*)(rowp + 24);   // d+3
    const float4 cs = *(const float4*)&tab[((size_t)sg << 5) + (d0 >> 1) + jq * 2];
#pragma unroll
    for (int h = 0; h < 8; ++h) {
      const float ve0 = b2f((unsigned short)x0[h]);
      const float vo0 = b2f((unsigned short)x1[h]);
      const float ve1 = b2f((unsigned short)x2[h]);
      const float vo1 = b2f((unsigned short)x3[h]);
      ushort4 o;
      o.x = f2b_bits((ve0 * cs.x - vo0 * cs.y) * scale);
      o.y = f2b_bits((vo0 * cs.x + ve0 * cs.y) * scale);
      o.z = f2b_bits((ve1 * cs.z - vo1 * cs.w) * scale);
      o.w = f2b_bits((vo1 * cs.z + ve1 * cs.w) * scale);
      *(ushort4*)(dst0 + (size_t)(bv_ * 8 + h) * (2048 * 64)
                       + (size_t)sg * 64 + d0 + jq * 4) = o;
    }
  }
}

// ------- output projection GEMM: 64x128 tiles, dbuf staging, f32 out -------

__global__ __launch_bounds__(256)
void gemm_o_kernel(const bf16* __restrict__ A, const bf16* __restrict__ Bt,
                   const float* __restrict__ bias, float* __restrict__ C)
{
  __shared__ bf16 As[2][64 * 32];
  __shared__ bf16 Bs[2][128 * 32];
  const int K = 512, N = 512;
  const int t = threadIdx.x;
  const int lane = t & 63;
  const int wave = t >> 6;
  const int wm = (wave >> 1) * 32;
  const int wn = (wave & 1) * 64;
  const int bm = blockIdx.x * 64;
  const int bn = blockIdx.y * 128;

  const int r4 = t >> 2;               // 0..63
  const int c8 = (t & 3) * 8;
  const bf16* Ag = A + (size_t)(bm + r4) * K + c8;
  const bf16* Bg = Bt + (size_t)(bn + r4) * K + c8;

  f32x4 acc[2][4] = {};
  const int rr = lane & 15;
  const int kg = (lane >> 4) * 8;

  auto stage = [&](int buf, int k0) {
    gload_lds16(Ag + k0, &As[buf][t * 8]);
    gload_lds16(Bg + k0, &Bs[buf][t * 8]);
    gload_lds16(Bg + (size_t)64 * K + k0, &Bs[buf][2048 + t * 8]);
  };

  stage(0, 0);
  int cur = 0;
  for (int k0 = 0; k0 < K; k0 += 32) {
    __syncthreads();
    if (k0 + 32 < K) stage(cur ^ 1, k0 + 32);
    bf16x8 af[2], bfr[4];
#pragma unroll
    for (int m = 0; m < 2; ++m) af[m] = *(const bf16x8*)&As[cur][(wm + m * 16 + rr) * 32 + kg];
#pragma unroll
    for (int n = 0; n < 4; ++n) bfr[n] = *(const bf16x8*)&Bs[cur][(wn + n * 16 + rr) * 32 + kg];
#pragma unroll
    for (int m = 0; m < 2; ++m)
#pragma unroll
      for (int n = 0; n < 4; ++n)
        acc[m][n] = mfma16(af[m], bfr[n], acc[m][n]);
    cur ^= 1;
  }

  const int rg = (lane >> 4) * 4;
#pragma unroll
  for (int n = 0; n < 4; ++n) {
    const int col = bn + wn + n * 16 + rr;
    const float bv = bias[col];
#pragma unroll
    for (int m = 0; m < 2; ++m)
#pragma unroll
      for (int r = 0; r < 4; ++r)
        C[(size_t)(bm + wm + m * 16 + rg + r) * N + col] = acc[m][n][r] + bv;
  }
}

// ---------------- causal flash attention (32x32 swapped, K-split) ----------------
// R14 state (best known): exp2-domain softmax with native v_exp_f32; P->A-frag
// via cvt_pk + permlane32_swap (T12); per-lane serial Ls (independent adds
// co-schedule with MFMA — R15's MFMA row-sum made a dependent MFMA chain and
// regressed +1.9us); shfl_xor epilogue reduce.

struct Item { unsigned char t, c, n, s; };  // tile, chunk, nblk, split?
__device__ __constant__ Item g_items[30] = {
  {5,0,12,0},{6,0,12,1},{7,0,12,1},{8,0,12,1},{9,0,12,1},{10,0,12,1},
  {11,0,12,1},{11,1,12,1},{12,0,12,1},{12,1,12,1},{13,0,12,1},{13,1,12,1},
  {14,0,12,1},{14,1,12,1},{15,0,12,1},{15,1,12,1},
  {4,0,10,0},{10,1,10,1},
  {3,0,8,0},{9,1,8,1},{15,2,8,1},
  {2,0,6,0},{8,1,6,1},{14,2,6,1},
  {1,0,4,0},{7,1,4,1},{13,2,4,1},
  {0,0,2,0},{6,1,2,1},{12,2,2,1}
};

__global__ __launch_bounds__(256, 4)
void attn_kernel(const bf16* __restrict__ Q, const bf16* __restrict__ K,
                 const bf16* __restrict__ VT, bf16* __restrict__ O,
                 bf16* __restrict__ PO, float* __restrict__ PML)
{
  __shared__ bf16 Kt[2][64 * 64];   // [k-row][d], chunk-XOR swizzled
  __shared__ bf16 Vt[2][64 * 64];   // [d][k],   chunk-XOR swizzled

  const int t = threadIdx.x;
  const int lane = t & 63;
  const int w = t >> 6;
  const int bvh = blockIdx.x;              // linear%8 = bvh%8 -> L2 locality
  const Item it = g_items[blockIdx.y];     // LPT: big items dispatched first
  const int tile = it.t, chunk = it.c, nblk = it.n, split = it.s;
  const int bv = bvh >> 3, h = bvh & 7;
  const size_t base = (size_t)bvh * (2048 * 64);

  const int q = lane & 31;                 // owned S^T column / V d-offset
  const int hi = lane >> 5;
  const int q0w = tile * 128 + w * 32;     // wave's first q-row
  const int qg = q0w + q;                  // lane's q-row
  const int kb0 = chunk * 12;              // first K-block of this chunk

  // Q fragments: B-operand of mfma32
  bf16x8 qf[4];
#pragma unroll
  for (int ds = 0; ds < 4; ++ds)
    qf[ds] = *(const bf16x8*)&Q[base + (size_t)(q0w + q) * 64 + ds * 16 + hi * 8];

  f32x16 o0 = {}, o1 = {};                 // O[q'][d], d-tiles 0/1
  float Mx = -INFINITY, Ls = 0.0f;

  const int sr = t >> 3;                   // staging row 0..31 (x2)
  const int sc = t & 7;                    // staging 16B chunk

  auto stage = [&](int buf, int kb) {
#pragma unroll
    for (int i = 0; i < 2; ++i) {
      int r = i * 32 + sr;
      int g = (sc ^ (r & 7)) * 8;          // pre-swizzled source col
      gload_lds16(&K[base + (size_t)(kb * 64 + r) * 64 + g], &Kt[buf][(i * 256 + t) * 8]);
      gload_lds16(&VT[base + (size_t)r * 2048 + kb * 64 + g], &Vt[buf][(i * 256 + t) * 8]);
    }
  };

  stage(0, kb0);
  int cur = 0;

#pragma unroll 1
  for (int i = 0; i < nblk; ++i) {
    const int kb = kb0 + i;
    __syncthreads();                       // implicit vmcnt(0): buf[cur] ready
    if (i + 1 < nblk) stage(cur ^ 1, kb + 1);

    if (kb * 64 <= q0w + 31) {             // wave has unmasked work
      // S^T = K Q  (64 k-rows x 32 q-cols)
      f32x16 s0 = {}, s1 = {};
      __builtin_amdgcn_s_setprio(1);
#pragma unroll
      for (int ds = 0; ds < 4; ++ds) {
        const int ck = ds * 2 + hi;
        bf16x8 k0 = *(const bf16x8*)&Kt[cur][q * 64 + ((ck ^ (q & 7)) * 8)];
        bf16x8 k1 = *(const bf16x8*)&Kt[cur][(32 + q) * 64 + ((ck ^ (q & 7)) * 8)];
        s0 = mfma32(k0, qf[ds], s0);
        s1 = mfma32(k1, qf[ds], s1);
      }
      __builtin_amdgcn_s_setprio(0);

      // mask whenever this K-block's max k exceeds the wave's MIN q-row
      if (kb * 64 + 63 > q0w) {
#pragma unroll
        for (int r = 0; r < 16; ++r) {
          const int k0i = kb * 64 + (r & 3) + 8 * (r >> 2) + 4 * hi;
          s0[r] = (k0i      <= qg) ? s0[r] : -INFINITY;
          s1[r] = (k0i + 32 <= qg) ? s1[r] : -INFINITY;
        }
      }

      // defer-max (THR = 8*log2e in exp2 domain)
      float pmax = -INFINITY;
#pragma unroll
      for (int r = 0; r < 16; ++r) pmax = fmaxf(pmax, fmaxf(s0[r], s1[r]));
      const float pm2 = fmaxf(pmax, __shfl_xor(pmax, 32));
      if (__any(pm2 > Mx + 11.541560327111707f)) {   // rare: full rescale
        const float newM = fmaxf(Mx, pm2);
        const float alpha = ex2(Mx - newM);
        Ls *= alpha;
        Mx = newM;
#pragma unroll
        for (int r = 0; r < 16; ++r) {
          const float ar = __shfl(alpha, (r & 3) + 8 * (r >> 2) + 4 * hi);
          o0[r] *= ar;
          o1[r] *= ar;
        }
      }

      // P = exp2(S^T - Mx): bare v_exp_f32 (Mx lane-local)
      float ls = 0.0f;
#pragma unroll
      for (int r = 0; r < 16; ++r) {
        s0[r] = ex2(s0[r] - Mx); ls += s0[r];
        s1[r] = ex2(s1[r] - Mx); ls += s1[r];
      }
      Ls += ls;

      // O += P V : P A-frags via cvt_pk + permlane32_swap (T12)
      __builtin_amdgcn_s_setprio(1);
#pragma unroll
      for (int T = 0; T < 2; ++T) {
#pragma unroll
        for (int e = 0; e < 2; ++e) {
          float v0, v1, v2, v3, v4, v5, v6, v7;
          if (T == 0) {
            v0 = s0[e*8+0]; v1 = s0[e*8+1]; v2 = s0[e*8+2]; v3 = s0[e*8+3];
            v4 = s0[e*8+4]; v5 = s0[e*8+5]; v6 = s0[e*8+6]; v7 = s0[e*8+7];
          } else {
            v0 = s1[e*8+0]; v1 = s1[e*8+1]; v2 = s1[e*8+2]; v3 = s1[e*8+3];
            v4 = s1[e*8+4]; v5 = s1[e*8+5]; v6 = s1[e*8+6]; v7 = s1[e*8+7];
          }
          const unsigned a = cvt_pk(v0, v1);
          const unsigned b = cvt_pk(v2, v3);
          const unsigned c = cvt_pk(v4, v5);
          const unsigned d = cvt_pk(v6, v7);
          const uintx2 s02 = __builtin_amdgcn_permlane32_swap(a, c, false, false);
          const uintx2 s13 = __builtin_amdgcn_permlane32_swap(b, d, false, false);
          union { unsigned u[4]; bf16x8 v; } pa;
          pa.u[0] = s02[0];  pa.u[1] = s13[0];
          pa.u[2] = s02[1];  pa.u[3] = s13[1];
          const int ck = (T * 2 + e) * 2 + hi;
          bf16x8 vf0 = *(const bf16x8*)&Vt[cur][q * 64 + ((ck ^ (q & 7)) * 8)];
          bf16x8 vf1 = *(const bf16x8*)&Vt[cur][(32 + q) * 64 + ((ck ^ (q & 7)) * 8)];
          o0 = mfma32(pa.v, vf0, o0);
          o1 = mfma32(pa.v, vf1, o1);
        }
      }
      __builtin_amdgcn_s_setprio(0);
    }
    cur ^= 1;
  }

  if (split) {
    // partial epilogue: raw bf16 O + per-row (m, l) -> workspace (m in exp2 dom)
    const int slot = (tile - 6) * 3 + chunk;          // 0..29
    bf16* po = PO + ((size_t)bvh * 30 + slot) * (128 * 64);
    float* pml = PML + ((size_t)bvh * 30 + slot) * 256;
    const float lt = Ls + __shfl_xor(Ls, 32);
    if (hi == 0) {
      pml[w * 32 + q] = Mx;                // Mx identical across the hi-pair
      pml[128 + w * 32 + q] = lt;
    }
#pragma unroll
    for (int r = 0; r < 16; ++r) {
      const int qp = (r & 3) + 8 * (r >> 2) + 4 * hi;
      po[(size_t)(w * 32 + qp) * 64 + q]      = __float2bfloat16(o0[r]);
      po[(size_t)(w * 32 + qp) * 64 + 32 + q] = __float2bfloat16(o1[r]);
    }
  } else {
    // direct epilogue: normalize, write O[bv][s][h*64+d]
    const float inv = 1.0f / (Ls + __shfl_xor(Ls, 32));
#pragma unroll
    for (int r = 0; r < 16; ++r) {
      const int qp = (r & 3) + 8 * (r >> 2) + 4 * hi;
      const float ir = __shfl(inv, qp);
      const size_t ob = ((size_t)bv * 2048 + q0w + qp) * 512 + h * 64;
      O[ob + q]      = __float2bfloat16(o0[r] * ir);
      O[ob + 32 + q] = __float2bfloat16(o1[r] * ir);
    }
  }
}

// ---------------- combine partials for split tiles (t = 6..15) ----------------

__global__ __launch_bounds__(256)
void combine_kernel(const bf16* __restrict__ PO, const float* __restrict__ PML,
                    bf16* __restrict__ O)
{
  const int t = 6 + blockIdx.x;            // tile 6..15
  const int bvh = blockIdx.y;
  const int nch = (t <= 11) ? 2 : 3;       // chunks per tile
  const int bv = bvh >> 3, h = bvh & 7;
  const int row = threadIdx.x >> 1;        // 0..127
  const int c0 = (threadIdx.x & 1) * 32;   // col half
  const size_t pbase = (size_t)bvh * 30 + (size_t)(t - 6) * 3;

  float mc[3], lc[3];
#pragma unroll
  for (int c = 0; c < 3; ++c) { mc[c] = -INFINITY; lc[c] = 0.0f; }
#pragma unroll
  for (int c = 0; c < 3; ++c) if (c < nch) {
    mc[c] = PML[(pbase + c) * 256 + row];
    lc[c] = PML[(pbase + c) * 256 + 128 + row];
  }
  const float m = fmaxf(fmaxf(mc[0], mc[1]), mc[2]);
  float wgt[3], l = 0.0f;
#pragma unroll
  for (int c = 0; c < 3; ++c) {
    wgt[c] = (c < nch) ? __builtin_amdgcn_exp2f(mc[c] - m) : 0.0f;  // exp2 dom
    l += wgt[c] * lc[c];
  }
  const float inv = 1.0f / l;

  float acc[32];
#pragma unroll
  for (int j = 0; j < 32; ++j) acc[j] = 0.0f;
#pragma unroll
  for (int c = 0; c < 3; ++c) if (c < nch) {
    const bf16* p = PO + (pbase + c) * (128 * 64) + (size_t)row * 64 + c0;
#pragma unroll
    for (int v = 0; v < 4; ++v) {
      bf16x8 x = *(const bf16x8*)&p[v * 8];
#pragma unroll
      for (int j = 0; j < 8; ++j) {
        const float f = __uint_as_float((unsigned)(unsigned short)x[j] << 16);
        acc[v * 8 + j] += wgt[c] * f;
      }
    }
  }
  const size_t ob = ((size_t)bv * 2048 + (size_t)t * 128 + row) * 512 + h * 64 + c0;
#pragma unroll
  for (int j = 0; j < 32; ++j) O[ob + j] = __float2bfloat16(acc[j] * inv);
}

// ---------------- launch ----------------

extern "C" void kernel_launch(void* const* d_in, const int* in_sizes, int n_in,
                              void* d_out, int out_size, void* d_ws, size_t ws_size,
                              hipStream_t stream)
{
  const float* x    = (const float*)d_in[1];
  const float* wqkv = (const float*)d_in[2];
  const float* bqkv = (const float*)d_in[3];
  const float* wo   = (const float*)d_in[4];
  const float* bo   = (const float*)d_in[5];
  float* out = (float*)d_out;

  char* p = (char*)d_ws;
  bf16* Xb   = (bf16*)p; p += (size_t)8192 * 512 * 2;      // dead after gemm_qkv
  bf16* Wqb  = (bf16*)p; p += (size_t)1536 * 512 * 2;
  bf16* Wob  = (bf16*)p; p += (size_t)512 * 512 * 2;
  bf16* SCR  = (bf16*)p; p += (size_t)8192 * 1536 * 2;     // PO scratch
  bf16* Qr   = (bf16*)p; p += (size_t)32 * 2048 * 64 * 2;
  bf16* Kr   = (bf16*)p; p += (size_t)32 * 2048 * 64 * 2;
  bf16* VTr  = (bf16*)p; p += (size_t)32 * 2048 * 64 * 2;
  bf16* Ob   = (bf16*)p; p += (size_t)8192 * 512 * 2;
  float2* tab = (float2*)p; p += (size_t)2048 * 32 * 8;

  // attention partials (stream-ordered reuse of dead regions):
  float* PML = (float*)Xb;                 // <1 MB  (Xb dead after gemm_qkv)
  bf16*  PO  = SCR;                        // ~16 MB

  prep_kernel<<<5376, 256, 0, stream>>>((const float4*)x, (const float4*)wqkv,
                                        (const float4*)wo, (ushort4*)Xb,
                                        (ushort4*)Wqb, (ushort4*)Wob, tab);

  gemm_qkv_kernel<<<dim3(64, 12), 256, 0, stream>>>(Xb, Wqb, bqkv, tab, Qr, Kr, VTr);
  attn_kernel<<<dim3(32, 30), 256, 0, stream>>>(Qr, Kr, VTr, Ob, PO, PML);
  combine_kernel<<<dim3(10, 32), 256, 0, stream>>>(PO, PML, Ob);
  gemm_o_kernel<<<dim3(128, 4), 256, 0, stream>>>(Ob, Wob, bo, out);
}

// Round 17
// 82.538 us; speedup vs baseline: 1.0245x; 1.0008x over previous
//
#include <hip/hip_runtime.h>
#include <hip/hip_bf16.h>

typedef __hip_bfloat16 bf16;
typedef __attribute__((ext_vector_type(8))) short bf16x8;    // 8 bf16 (MFMA A/B frag)
typedef __attribute__((ext_vector_type(4))) float f32x4;     // 16x16 C/D frag
typedef __attribute__((ext_vector_type(16))) float f32x16;   // 32x32 C/D frag
typedef __attribute__((ext_vector_type(2))) unsigned uintx2; // permlane32_swap ret

#define DEV static __device__ __forceinline__

DEV void gload_lds16(const void* g, void* l) {
  __builtin_amdgcn_global_load_lds((const __attribute__((address_space(1))) void*)g,
                                   (__attribute__((address_space(3))) void*)l, 16, 0, 0);
}

DEV f32x4 mfma16(bf16x8 a, bf16x8 b, f32x4 c) {
  return __builtin_amdgcn_mfma_f32_16x16x32_bf16(a, b, c, 0, 0, 0);
}
DEV f32x16 mfma32(bf16x8 a, bf16x8 b, f32x16 c) {
  return __builtin_amdgcn_mfma_f32_32x32x16_bf16(a, b, c, 0, 0, 0);
}

DEV float ex2(float x) { return __builtin_amdgcn_exp2f(x); }  // bare v_exp_f32

DEV unsigned cvt_pk(float lo, float hi) {   // packed f32x2 -> bf16x2 (RNE)
  unsigned r;
  asm("v_cvt_pk_bf16_f32 %0, %1, %2" : "=v"(r) : "v"(lo), "v"(hi));
  return r;
}

DEV unsigned short f2b_bits(float f) {  // RNE f32->bf16 (inputs are finite)
  unsigned int u = __float_as_uint(f);
  return (unsigned short)((u + 0x7fffu + ((u >> 16) & 1u)) >> 16);
}

DEV float b2f(unsigned short b) { return __uint_as_float((unsigned)b << 16); }

// ------- prep: merged f32->bf16 (X, Wqkv, Wo) + RoPE cos/sin table -------

__global__ void prep_kernel(const float4* __restrict__ x, const float4* __restrict__ wq,
                            const float4* __restrict__ wo, ushort4* __restrict__ xb,
                            ushort4* __restrict__ wqb, ushort4* __restrict__ wob,
                            float2* __restrict__ tab) {
  int i = blockIdx.x * 256 + threadIdx.x;
  if (i >= 1310720) {                     // rope table part (256 trailing blocks)
    int idx = i - 1310720;                // s*32 + j
    int s = idx >> 5, j = idx & 31;
    float inv = exp2f(-(float)(2 * j) * (13.287712379549449f / 64.0f));
    float a = (float)s * inv;
    tab[idx] = make_float2(cosf(a), sinf(a));
    return;
  }
  const float4* s; ushort4* d; int off;
  if (i < 1048576)      { s = x;  d = xb;  off = i; }            // 8192*512/4
  else if (i < 1245184) { s = wq; d = wqb; off = i - 1048576; }  // +1536*512/4
  else                  { s = wo; d = wob; off = i - 1245184; }  // +512*512/4
  float4 v = s[off];
  ushort4 o;
  o.x = f2b_bits(v.x); o.y = f2b_bits(v.y); o.z = f2b_bits(v.z); o.w = f2b_bits(v.w);
  d[off] = o;
}

// ---------------- QKV GEMM with fused RoPE / V-transpose epilogue ----------------
// R16 internals. NEW: T1 XCD-aware 1D block swizzle (bijective, 768%8==0):
// XCD x (= nb&7 under round-robin dispatch) owns M-tiles [8x, 8x+8) for ALL
// 12 N-tiles -> per-XCD A-panel slice = 1 MB, resident in the 4 MB XCD L2,
// fetched from HBM once instead of ~12x.

__global__ __launch_bounds__(256)
void gemm_qkv_kernel(const bf16* __restrict__ A, const bf16* __restrict__ Bt,
                     const float* __restrict__ bias, const float2* __restrict__ tab,
                     bf16* __restrict__ Qo, bf16* __restrict__ Ko, bf16* __restrict__ VTo)
{
  __shared__ bf16 SH[128 * 136];        // 34 KB; K-loop staging aliases front 32 KB
  const int K = 512;
  const int t = threadIdx.x;
  const int lane = t & 63;
  const int wave = t >> 6;
  const int wm = (wave >> 1) * 64;
  const int wn = (wave & 1) * 64;

  // T1 swizzle: nb&7 = XCD, jj&7 = M-tile within XCD band, jj>>3 = N-tile
  const int nb = blockIdx.x;
  const int jj = nb >> 3;
  const int bm = (((nb & 7) << 3) | (jj & 7)) * 128;
  const int bn = (jj >> 3) * 128;
  const int qkv = bn >> 9;              // 0=Q 1=K 2=V (block-uniform)
  const int local0 = bn & 511;

  const int r4 = t >> 2;
  const int c8 = (t & 3) * 8;
  const bf16* Ag = A + (size_t)(bm + r4) * K + c8;
  const bf16* Bg = Bt + (size_t)(bn + r4) * K + c8;

  f32x4 acc[4][4] = {};
  const int rr = lane & 15;
  const int kg = (lane >> 4) * 8;

  // staging layout (elements): A buf0 @0, A buf1 @4096, B buf0 @8192, B buf1 @12288
  auto stage = [&](int buf, int k0) {
    bf16* Asl = SH + buf * 4096 + t * 8;
    bf16* Bsl = SH + 8192 + buf * 4096 + t * 8;
    gload_lds16(Ag + k0, Asl);
    gload_lds16(Ag + (size_t)64 * K + k0, Asl + 2048);
    gload_lds16(Bg + k0, Bsl);
    gload_lds16(Bg + (size_t)64 * K + k0, Bsl + 2048);
  };

  stage(0, 0);
  int cur = 0;
  for (int k0 = 0; k0 < K; k0 += 32) {
    __syncthreads();                    // implicit vmcnt(0): buf[cur] ready
    if (k0 + 32 < K) stage(cur ^ 1, k0 + 32);   // overlap next loads w/ compute
    const bf16* Asb = SH + cur * 4096;
    const bf16* Bsb = SH + 8192 + cur * 4096;
    bf16x8 af[4], bfr[4];
#pragma unroll
    for (int m = 0; m < 4; ++m) af[m] = *(const bf16x8*)&Asb[(wm + m * 16 + rr) * 32 + kg];
#pragma unroll
    for (int n = 0; n < 4; ++n) bfr[n] = *(const bf16x8*)&Bsb[(wn + n * 16 + rr) * 32 + kg];
#pragma unroll
    for (int m = 0; m < 4; ++m)
#pragma unroll
      for (int n = 0; n < 4; ++n)
        acc[m][n] = mfma16(af[m], bfr[n], acc[m][n]);
    cur ^= 1;
  }
  __syncthreads();                      // all reads of staging done; SH reusable

  const int rg = (lane >> 4) * 4;
  float bv4[4];
#pragma unroll
  for (int n = 0; n < 4; ++n) bv4[n] = bias[bn + wn + n * 16 + rr];

  // phase 1: biased tile -> LDS [s][136]
#pragma unroll
  for (int n = 0; n < 4; ++n)
#pragma unroll
    for (int m = 0; m < 4; ++m)
#pragma unroll
      for (int r = 0; r < 4; ++r)
        SH[(wm + m * 16 + rg + r) * 136 + (wn + n * 16 + rr)] =
            __float2bfloat16(acc[m][n][r] + bv4[n]);
  __syncthreads();

  const int bv_ = bm >> 11;             // which (b,v)
  const int s0 = bm & 2047;
  const int d0 = local0 >> 3;           // 0,16,32,48

  if (qkv == 2) {
    // V: transpose out of LDS. thread = (local feature p, s-half).
    const int p = t & 127;              // p = dl*8 + hh
    const int sh = (t >> 7) * 64;
    const int dl = p >> 3, hh = p & 7;
    bf16* dst = VTo + (size_t)(bv_ * 8 + hh) * (2048 * 64)
                    + (size_t)(d0 + dl) * 2048 + s0 + sh;
#pragma unroll
    for (int g = 0; g < 8; ++g) {
      union { unsigned short u[8]; ushort4 q[2]; } o;
#pragma unroll
      for (int k = 0; k < 8; ++k)
        o.u[k] = *(const unsigned short*)&SH[(sh + g * 8 + k) * 136 + p];
      *(ushort4*)(dst + g * 8)     = o.q[0];
      *(ushort4*)(dst + g * 8 + 4) = o.q[1];
    }
    return;
  }

  // phase 2 (Q/K): rope, vectorized. unit = (s-row sl, d-quad jq)
  bf16* dst0 = (qkv == 0) ? Qo : Ko;
  const float scale = (qkv == 0) ? 0.18033688011112042f : 1.0f;  // Q: 1/8*log2(e)
#pragma unroll
  for (int pass = 0; pass < 2; ++pass) {
    const int u = pass * 256 + t;
    const int sl = u >> 2;              // 0..127
    const int jq = u & 3;               // d-quad: d = d0+4jq .. +3
    const int sg = s0 + sl;
    const bf16* rowp = &SH[sl * 136 + jq * 32];
    bf16x8 x0 = *(const bf16x8*)(rowp);        // d = d0+4jq (h=0..7)
    bf16x8 x1 = *(const bf16x8*)(rowp + 8);    // d+1
    bf16x8 x2 = *(const bf16x8*)(rowp + 16);   // d+2
    bf16x8 x3 = *(const bf16x8*)(rowp + 24);   // d+3
    const float4 cs = *(const float4*)&tab[((size_t)sg << 5) + (d0 >> 1) + jq * 2];
#pragma unroll
    for (int h = 0; h < 8; ++h) {
      const float ve0 = b2f((unsigned short)x0[h]);
      const float vo0 = b2f((unsigned short)x1[h]);
      const float ve1 = b2f((unsigned short)x2[h]);
      const float vo1 = b2f((unsigned short)x3[h]);
      ushort4 o;
      o.x = f2b_bits((ve0 * cs.x - vo0 * cs.y) * scale);
      o.y = f2b_bits((vo0 * cs.x + ve0 * cs.y) * scale);
      o.z = f2b_bits((ve1 * cs.z - vo1 * cs.w) * scale);
      o.w = f2b_bits((vo1 * cs.z + ve1 * cs.w) * scale);
      *(ushort4*)(dst0 + (size_t)(bv_ * 8 + h) * (2048 * 64)
                       + (size_t)sg * 64 + d0 + jq * 4) = o;
    }
  }
}

// ------- output projection GEMM: 64x128 tiles, dbuf staging, f32 out -------
// R16 internals + T1 XCD swizzle (512%8==0, bijective): XCD x owns M-tiles
// [16x, 16x+16) for all 4 N-tiles -> per-XCD A slice 1 MB, L2-resident.

__global__ __launch_bounds__(256)
void gemm_o_kernel(const bf16* __restrict__ A, const bf16* __restrict__ Bt,
                   const float* __restrict__ bias, float* __restrict__ C)
{
  __shared__ bf16 As[2][64 * 32];
  __shared__ bf16 Bs[2][128 * 32];
  const int K = 512, N = 512;
  const int t = threadIdx.x;
  const int lane = t & 63;
  const int wave = t >> 6;
  const int wm = (wave >> 1) * 32;
  const int wn = (wave & 1) * 64;

  const int nb = blockIdx.x;
  const int jj = nb >> 3;
  const int bm = ((nb & 7) * 16 + (jj & 15)) * 64;
  const int bn = (jj >> 4) * 128;

  const int r4 = t >> 2;               // 0..63
  const int c8 = (t & 3) * 8;
  const bf16* Ag = A + (size_t)(bm + r4) * K + c8;
  const bf16* Bg = Bt + (size_t)(bn + r4) * K + c8;

  f32x4 acc[2][4] = {};
  const int rr = lane & 15;
  const int kg = (lane >> 4) * 8;

  auto stage = [&](int buf, int k0) {
    gload_lds16(Ag + k0, &As[buf][t * 8]);
    gload_lds16(Bg + k0, &Bs[buf][t * 8]);
    gload_lds16(Bg + (size_t)64 * K + k0, &Bs[buf][2048 + t * 8]);
  };

  stage(0, 0);
  int cur = 0;
  for (int k0 = 0; k0 < K; k0 += 32) {
    __syncthreads();
    if (k0 + 32 < K) stage(cur ^ 1, k0 + 32);
    bf16x8 af[2], bfr[4];
#pragma unroll
    for (int m = 0; m < 2; ++m) af[m] = *(const bf16x8*)&As[cur][(wm + m * 16 + rr) * 32 + kg];
#pragma unroll
    for (int n = 0; n < 4; ++n) bfr[n] = *(const bf16x8*)&Bs[cur][(wn + n * 16 + rr) * 32 + kg];
#pragma unroll
    for (int m = 0; m < 2; ++m)
#pragma unroll
      for (int n = 0; n < 4; ++n)
        acc[m][n] = mfma16(af[m], bfr[n], acc[m][n]);
    cur ^= 1;
  }

  const int rg = (lane >> 4) * 4;
#pragma unroll
  for (int n = 0; n < 4; ++n) {
    const int col = bn + wn + n * 16 + rr;
    const float bv = bias[col];
#pragma unroll
    for (int m = 0; m < 2; ++m)
#pragma unroll
      for (int r = 0; r < 4; ++r)
        C[(size_t)(bm + wm + m * 16 + rg + r) * N + col] = acc[m][n][r] + bv;
  }
}

// ---------------- causal flash attention (32x32 swapped, K-split) ----------------
// R16/R14 state (best known) — untouched.

struct Item { unsigned char t, c, n, s; };  // tile, chunk, nblk, split?
__device__ __constant__ Item g_items[30] = {
  {5,0,12,0},{6,0,12,1},{7,0,12,1},{8,0,12,1},{9,0,12,1},{10,0,12,1},
  {11,0,12,1},{11,1,12,1},{12,0,12,1},{12,1,12,1},{13,0,12,1},{13,1,12,1},
  {14,0,12,1},{14,1,12,1},{15,0,12,1},{15,1,12,1},
  {4,0,10,0},{10,1,10,1},
  {3,0,8,0},{9,1,8,1},{15,2,8,1},
  {2,0,6,0},{8,1,6,1},{14,2,6,1},
  {1,0,4,0},{7,1,4,1},{13,2,4,1},
  {0,0,2,0},{6,1,2,1},{12,2,2,1}
};

__global__ __launch_bounds__(256, 4)
void attn_kernel(const bf16* __restrict__ Q, const bf16* __restrict__ K,
                 const bf16* __restrict__ VT, bf16* __restrict__ O,
                 bf16* __restrict__ PO, float* __restrict__ PML)
{
  __shared__ bf16 Kt[2][64 * 64];   // [k-row][d], chunk-XOR swizzled
  __shared__ bf16 Vt[2][64 * 64];   // [d][k],   chunk-XOR swizzled

  const int t = threadIdx.x;
  const int lane = t & 63;
  const int w = t >> 6;
  const int bvh = blockIdx.x;              // linear%8 = bvh%8 -> L2 locality
  const Item it = g_items[blockIdx.y];     // LPT: big items dispatched first
  const int tile = it.t, chunk = it.c, nblk = it.n, split = it.s;
  const int bv = bvh >> 3, h = bvh & 7;
  const size_t base = (size_t)bvh * (2048 * 64);

  const int q = lane & 31;                 // owned S^T column / V d-offset
  const int hi = lane >> 5;
  const int q0w = tile * 128 + w * 32;     // wave's first q-row
  const int qg = q0w + q;                  // lane's q-row
  const int kb0 = chunk * 12;              // first K-block of this chunk

  // Q fragments: B-operand of mfma32
  bf16x8 qf[4];
#pragma unroll
  for (int ds = 0; ds < 4; ++ds)
    qf[ds] = *(const bf16x8*)&Q[base + (size_t)(q0w + q) * 64 + ds * 16 + hi * 8];

  f32x16 o0 = {}, o1 = {};                 // O[q'][d], d-tiles 0/1
  float Mx = -INFINITY, Ls = 0.0f;

  const int sr = t >> 3;                   // staging row 0..31 (x2)
  const int sc = t & 7;                    // staging 16B chunk

  auto stage = [&](int buf, int kb) {
#pragma unroll
    for (int i = 0; i < 2; ++i) {
      int r = i * 32 + sr;
      int g = (sc ^ (r & 7)) * 8;          // pre-swizzled source col
      gload_lds16(&K[base + (size_t)(kb * 64 + r) * 64 + g], &Kt[buf][(i * 256 + t) * 8]);
      gload_lds16(&VT[base + (size_t)r * 2048 + kb * 64 + g], &Vt[buf][(i * 256 + t) * 8]);
    }
  };

  stage(0, kb0);
  int cur = 0;

#pragma unroll 1
  for (int i = 0; i < nblk; ++i) {
    const int kb = kb0 + i;
    __syncthreads();                       // implicit vmcnt(0): buf[cur] ready
    if (i + 1 < nblk) stage(cur ^ 1, kb + 1);

    if (kb * 64 <= q0w + 31) {             // wave has unmasked work
      // S^T = K Q  (64 k-rows x 32 q-cols)
      f32x16 s0 = {}, s1 = {};
      __builtin_amdgcn_s_setprio(1);
#pragma unroll
      for (int ds = 0; ds < 4; ++ds) {
        const int ck = ds * 2 + hi;
        bf16x8 k0 = *(const bf16x8*)&Kt[cur][q * 64 + ((ck ^ (q & 7)) * 8)];
        bf16x8 k1 = *(const bf16x8*)&Kt[cur][(32 + q) * 64 + ((ck ^ (q & 7)) * 8)];
        s0 = mfma32(k0, qf[ds], s0);
        s1 = mfma32(k1, qf[ds], s1);
      }
      __builtin_amdgcn_s_setprio(0);

      // mask whenever this K-block's max k exceeds the wave's MIN q-row
      if (kb * 64 + 63 > q0w) {
#pragma unroll
        for (int r = 0; r < 16; ++r) {
          const int k0i = kb * 64 + (r & 3) + 8 * (r >> 2) + 4 * hi;
          s0[r] = (k0i      <= qg) ? s0[r] : -INFINITY;
          s1[r] = (k0i + 32 <= qg) ? s1[r] : -INFINITY;
        }
      }

      // defer-max (THR = 8*log2e in exp2 domain)
      float pmax = -INFINITY;
#pragma unroll
      for (int r = 0; r < 16; ++r) pmax = fmaxf(pmax, fmaxf(s0[r], s1[r]));
      const float pm2 = fmaxf(pmax, __shfl_xor(pmax, 32));
      if (__any(pm2 > Mx + 11.541560327111707f)) {   // rare: full rescale
        const float newM = fmaxf(Mx, pm2);
        const float alpha = ex2(Mx - newM);
        Ls *= alpha;
        Mx = newM;
#pragma unroll
        for (int r = 0; r < 16; ++r) {
          const float ar = __shfl(alpha, (r & 3) + 8 * (r >> 2) + 4 * hi);
          o0[r] *= ar;
          o1[r] *= ar;
        }
      }

      // P = exp2(S^T - Mx): bare v_exp_f32 (Mx lane-local)
      float ls = 0.0f;
#pragma unroll
      for (int r = 0; r < 16; ++r) {
        s0[r] = ex2(s0[r] - Mx); ls += s0[r];
        s1[r] = ex2(s1[r] - Mx); ls += s1[r];
      }
      Ls += ls;

      // O += P V : P A-frags via cvt_pk + permlane32_swap (T12)
      __builtin_amdgcn_s_setprio(1);
#pragma unroll
      for (int T = 0; T < 2; ++T) {
#pragma unroll
        for (int e = 0; e < 2; ++e) {
          float v0, v1, v2, v3, v4, v5, v6, v7;
          if (T == 0) {
            v0 = s0[e*8+0]; v1 = s0[e*8+1]; v2 = s0[e*8+2]; v3 = s0[e*8+3];
            v4 = s0[e*8+4]; v5 = s0[e*8+5]; v6 = s0[e*8+6]; v7 = s0[e*8+7];
          } else {
            v0 = s1[e*8+0]; v1 = s1[e*8+1]; v2 = s1[e*8+2]; v3 = s1[e*8+3];
            v4 = s1[e*8+4]; v5 = s1[e*8+5]; v6 = s1[e*8+6]; v7 = s1[e*8+7];
          }
          const unsigned a = cvt_pk(v0, v1);
          const unsigned b = cvt_pk(v2, v3);
          const unsigned c = cvt_pk(v4, v5);
          const unsigned d = cvt_pk(v6, v7);
          const uintx2 s02 = __builtin_amdgcn_permlane32_swap(a, c, false, false);
          const uintx2 s13 = __builtin_amdgcn_permlane32_swap(b, d, false, false);
          union { unsigned u[4]; bf16x8 v; } pa;
          pa.u[0] = s02[0];  pa.u[1] = s13[0];
          pa.u[2] = s02[1];  pa.u[3] = s13[1];
          const int ck = (T * 2 + e) * 2 + hi;
          bf16x8 vf0 = *(const bf16x8*)&Vt[cur][q * 64 + ((ck ^ (q & 7)) * 8)];
          bf16x8 vf1 = *(const bf16x8*)&Vt[cur][(32 + q) * 64 + ((ck ^ (q & 7)) * 8)];
          o0 = mfma32(pa.v, vf0, o0);
          o1 = mfma32(pa.v, vf1, o1);
        }
      }
      __builtin_amdgcn_s_setprio(0);
    }
    cur ^= 1;
  }

  if (split) {
    // partial epilogue: raw bf16 O + per-row (m, l) -> workspace (m in exp2 dom)
    const int slot = (tile - 6) * 3 + chunk;          // 0..29
    bf16* po = PO + ((size_t)bvh * 30 + slot) * (128 * 64);
    float* pml = PML + ((size_t)bvh * 30 + slot) * 256;
    const float lt = Ls + __shfl_xor(Ls, 32);
    if (hi == 0) {
      pml[w * 32 + q] = Mx;                // Mx identical across the hi-pair
      pml[128 + w * 32 + q] = lt;
    }
#pragma unroll
    for (int r = 0; r < 16; ++r) {
      const int qp = (r & 3) + 8 * (r >> 2) + 4 * hi;
      po[(size_t)(w * 32 + qp) * 64 + q]      = __float2bfloat16(o0[r]);
      po[(size_t)(w * 32 + qp) * 64 + 32 + q] = __float2bfloat16(o1[r]);
    }
  } else {
    // direct epilogue: normalize, write O[bv][s][h*64+d]
    const float inv = 1.0f / (Ls + __shfl_xor(Ls, 32));
#pragma unroll
    for (int r = 0; r < 16; ++r) {
      const int qp = (r & 3) + 8 * (r >> 2) + 4 * hi;
      const float ir = __shfl(inv, qp);
      const size_t ob = ((size_t)bv * 2048 + q0w + qp) * 512 + h * 64;
      O[ob + q]      = __float2bfloat16(o0[r] * ir);
      O[ob + 32 + q] = __float2bfloat16(o1[r] * ir);
    }
  }
}

// ---------------- combine partials for split tiles (t = 6..15) ----------------

__global__ __launch_bounds__(256)
void combine_kernel(const bf16* __restrict__ PO, const float* __restrict__ PML,
                    bf16* __restrict__ O)
{
  const int t = 6 + blockIdx.x;            // tile 6..15
  const int bvh = blockIdx.y;
  const int nch = (t <= 11) ? 2 : 3;       // chunks per tile
  const int bv = bvh >> 3, h = bvh & 7;
  const int row = threadIdx.x >> 1;        // 0..127
  const int c0 = (threadIdx.x & 1) * 32;   // col half
  const size_t pbase = (size_t)bvh * 30 + (size_t)(t - 6) * 3;

  float mc[3], lc[3];
#pragma unroll
  for (int c = 0; c < 3; ++c) { mc[c] = -INFINITY; lc[c] = 0.0f; }
#pragma unroll
  for (int c = 0; c < 3; ++c) if (c < nch) {
    mc[c] = PML[(pbase + c) * 256 + row];
    lc[c] = PML[(pbase + c) * 256 + 128 + row];
  }
  const float m = fmaxf(fmaxf(mc[0], mc[1]), mc[2]);
  float wgt[3], l = 0.0f;
#pragma unroll
  for (int c = 0; c < 3; ++c) {
    wgt[c] = (c < nch) ? __builtin_amdgcn_exp2f(mc[c] - m) : 0.0f;  // exp2 dom
    l += wgt[c] * lc[c];
  }
  const float inv = 1.0f / l;

  float acc[32];
#pragma unroll
  for (int j = 0; j < 32; ++j) acc[j] = 0.0f;
#pragma unroll
  for (int c = 0; c < 3; ++c) if (c < nch) {
    const bf16* p = PO + (pbase + c) * (128 * 64) + (size_t)row * 64 + c0;
#pragma unroll
    for (int v = 0; v < 4; ++v) {
      bf16x8 x = *(const bf16x8*)&p[v * 8];
#pragma unroll
      for (int j = 0; j < 8; ++j) {
        const float f = __uint_as_float((unsigned)(unsigned short)x[j] << 16);
        acc[v * 8 + j] += wgt[c] * f;
      }
    }
  }
  const size_t ob = ((size_t)bv * 2048 + (size_t)t * 128 + row) * 512 + h * 64 + c0;
#pragma unroll
  for (int j = 0; j < 32; ++j) O[ob + j] = __float2bfloat16(acc[j] * inv);
}

// ---------------- launch ----------------

extern "C" void kernel_launch(void* const* d_in, const int* in_sizes, int n_in,
                              void* d_out, int out_size, void* d_ws, size_t ws_size,
                              hipStream_t stream)
{
  const float* x    = (const float*)d_in[1];
  const float* wqkv = (const float*)d_in[2];
  const float* bqkv = (const float*)d_in[3];
  const float* wo   = (const float*)d_in[4];
  const float* bo   = (const float*)d_in[5];
  float* out = (float*)d_out;

  char* p = (char*)d_ws;
  bf16* Xb   = (bf16*)p; p += (size_t)8192 * 512 * 2;      // dead after gemm_qkv
  bf16* Wqb  = (bf16*)p; p += (size_t)1536 * 512 * 2;
  bf16* Wob  = (bf16*)p; p += (size_t)512 * 512 * 2;
  bf16* SCR  = (bf16*)p; p += (size_t)8192 * 1536 * 2;     // PO scratch
  bf16* Qr   = (bf16*)p; p += (size_t)32 * 2048 * 64 * 2;
  bf16* Kr   = (bf16*)p; p += (size_t)32 * 2048 * 64 * 2;
  bf16* VTr  = (bf16*)p; p += (size_t)32 * 2048 * 64 * 2;
  bf16* Ob   = (bf16*)p; p += (size_t)8192 * 512 * 2;
  float2* tab = (float2*)p; p += (size_t)2048 * 32 * 8;

  // attention partials (stream-ordered reuse of dead regions):
  float* PML = (float*)Xb;                 // <1 MB  (Xb dead after gemm_qkv)
  bf16*  PO  = SCR;                        // ~16 MB

  prep_kernel<<<5376, 256, 0, stream>>>((const float4*)x, (const float4*)wqkv,
                                        (const float4*)wo, (ushort4*)Xb,
                                        (ushort4*)Wqb, (ushort4*)Wob, tab);

  gemm_qkv_kernel<<<768, 256, 0, stream>>>(Xb, Wqb, bqkv, tab, Qr, Kr, VTr);
  attn_kernel<<<dim3(32, 30), 256, 0, stream>>>(Qr, Kr, VTr, Ob, PO, PML);
  combine_kernel<<<dim3(10, 32), 256, 0, stream>>>(PO, PML, Ob);
  gemm_o_kernel<<<512, 256, 0, stream>>>(Ob, Wob, bo, out);
}